// Round 1
// baseline (1354.667 us; speedup 1.0000x reference)
//
#include <hip/hip_runtime.h>

#define T_TOK 8192
#define H_DIM 1024
#define E_NUM 16
#define I_DIM 2048
#define N1    4096
#define BK    64
#define MAX_TILES 208
#define MAX_ROWS (MAX_TILES * 128)

// ctrl layout (int32 indices)
#define CTRL_COUNTS 0
#define CTRL_FILL   32
#define CTRL_OFFS   64
#define CTRL_TOTAL  96
#define CTRL_TE     128
#define CTRL_TR     (128 + MAX_TILES)
#define CTRL_INTS   (128 + 2 * MAX_TILES)

typedef __attribute__((ext_vector_type(8))) short short8;
typedef __attribute__((ext_vector_type(4))) float f32x4;

// ---- workspace layout (bytes) ----
static const size_t OFF_WT1  = 0;                                          // [16][4096][1024] bf16
static const size_t OFF_WT2  = OFF_WT1  + (size_t)E_NUM * N1 * H_DIM * 2;  // [16][1024][2048] bf16
static const size_t OFF_WS1T = OFF_WT2  + (size_t)E_NUM * H_DIM * I_DIM * 2; // [4096][1024]
static const size_t OFF_WS2T = OFF_WS1T + (size_t)N1 * H_DIM * 2;          // [1024][2048]
static const size_t OFF_XB   = OFF_WS2T + (size_t)I_DIM * H_DIM * 2;       // [8192][1024] bf16
static const size_t OFF_HID  = OFF_XB   + (size_t)T_TOK * H_DIM * 2;       // [MAX_ROWS][2048] bf16
static const size_t OFF_RIT  = OFF_HID  + (size_t)MAX_ROWS * I_DIM * 2;    // int[MAX_ROWS]
static const size_t OFF_RIW  = OFF_RIT  + (size_t)MAX_ROWS * 4;            // float[MAX_ROWS]
static const size_t OFF_CTRL = OFF_RIW  + (size_t)MAX_ROWS * 4;            // int[CTRL_INTS]
static const size_t OFF_TKI  = OFF_CTRL + (size_t)CTRL_INTS * 4;           // int[T][2]
static const size_t OFF_TKW  = OFF_TKI  + (size_t)T_TOK * 2 * 4;           // float[T][2]

__device__ __forceinline__ unsigned short f2bf(float f) {
    unsigned int u = __float_as_uint(f);
    u = (u + 0x7FFFu + ((u >> 16) & 1u)) >> 16;   // RNE
    return (unsigned short)u;
}

// ---------- transpose + f32->bf16: dst[b][c][r] = bf16(src[b][r][c]) ----------
__global__ void transpose_cvt_kernel(const float* __restrict__ src,
                                     unsigned short* __restrict__ dst,
                                     int R, int C) {
    __shared__ float tile[64][65];
    const size_t base = (size_t)blockIdx.z * R * C;
    const int c0 = blockIdx.x * 64, r0 = blockIdx.y * 64;
    const int tid = threadIdx.x;
    #pragma unroll
    for (int i = 0; i < 16; i++) {
        int idx = tid + i * 256;
        int rl = idx >> 6, cl = idx & 63;
        tile[rl][cl] = src[base + (size_t)(r0 + rl) * C + (c0 + cl)];
    }
    __syncthreads();
    #pragma unroll
    for (int i = 0; i < 8; i++) {
        int p = tid + i * 256;
        int cr = p >> 5, h2 = (p & 31) * 2;
        unsigned int v = (unsigned int)f2bf(tile[h2][cr]) |
                         ((unsigned int)f2bf(tile[h2 + 1][cr]) << 16);
        *(unsigned int*)(dst + base + (size_t)(c0 + cr) * R + (r0 + h2)) = v;
    }
}

// ---------- x f32 -> bf16 (no transpose) ----------
__global__ void cvt_x_kernel(const float* __restrict__ x, unsigned short* __restrict__ xb) {
    size_t i = (size_t)blockIdx.x * 256 + threadIdx.x;   // one per 8 elems
    const float4* xp = (const float4*)x;
    float4 v0 = xp[i * 2], v1 = xp[i * 2 + 1];
    uint4 o;
    o.x = (unsigned)f2bf(v0.x) | ((unsigned)f2bf(v0.y) << 16);
    o.y = (unsigned)f2bf(v0.z) | ((unsigned)f2bf(v0.w) << 16);
    o.z = (unsigned)f2bf(v1.x) | ((unsigned)f2bf(v1.y) << 16);
    o.w = (unsigned)f2bf(v1.z) | ((unsigned)f2bf(v1.w) << 16);
    ((uint4*)xb)[i] = o;
}

// ---------- router: f32 logits, sigmoid, top-2 (lax.top_k tie semantics), renorm ----------
__global__ void router_kernel(const float* __restrict__ x, const float* __restrict__ gw,
                              int* __restrict__ tki, float* __restrict__ tkw,
                              int* __restrict__ ctrl) {
    const int t = blockIdx.x;
    const int lane = threadIdx.x;
    float acc[16];
    #pragma unroll
    for (int e = 0; e < 16; e++) acc[e] = 0.f;
    const float* xr = x + (size_t)t * H_DIM;
    for (int h = lane; h < H_DIM; h += 64) {
        float xv = xr[h];
        const float4* g4 = (const float4*)(gw + h * 16);
        float4 a = g4[0], b = g4[1], c = g4[2], d = g4[3];
        acc[0] += xv * a.x; acc[1] += xv * a.y; acc[2]  += xv * a.z; acc[3]  += xv * a.w;
        acc[4] += xv * b.x; acc[5] += xv * b.y; acc[6]  += xv * b.z; acc[7]  += xv * b.w;
        acc[8] += xv * c.x; acc[9] += xv * c.y; acc[10] += xv * c.z; acc[11] += xv * c.w;
        acc[12]+= xv * d.x; acc[13]+= xv * d.y; acc[14] += xv * d.z; acc[15] += xv * d.w;
    }
    #pragma unroll
    for (int e = 0; e < 16; e++) {
        #pragma unroll
        for (int s = 32; s > 0; s >>= 1) acc[e] += __shfl_xor(acc[e], s);
    }
    if (lane == 0) {
        float sc[16];
        #pragma unroll
        for (int e = 0; e < 16; e++) sc[e] = 1.f / (1.f + __expf(-acc[e]));
        int i1 = 0;
        #pragma unroll
        for (int e = 1; e < 16; e++) if (sc[e] > sc[i1]) i1 = e;
        int i2 = (i1 == 0) ? 1 : 0;
        #pragma unroll
        for (int e = 0; e < 16; e++) if (e != i1 && sc[e] > sc[i2]) i2 = e;
        float s = sc[i1] + sc[i2];
        tki[2 * t] = i1; tki[2 * t + 1] = i2;
        tkw[2 * t] = sc[i1] / s; tkw[2 * t + 1] = sc[i2] / s;
        atomicAdd(&ctrl[CTRL_COUNTS + i1], 1);
        atomicAdd(&ctrl[CTRL_COUNTS + i2], 1);
    }
}

// ---------- prefix: padded offsets + tile table (serial, tiny) ----------
__global__ void prefix_kernel(int* __restrict__ ctrl) {
    if (threadIdx.x != 0) return;
    int off = 0, tc = 0;
    for (int e = 0; e <= 16; e++) {
        int c = (e == 16) ? T_TOK : ctrl[CTRL_COUNTS + e];
        ctrl[CTRL_OFFS + e] = off;
        int nt = (c + 127) >> 7;
        for (int i = 0; i < nt; i++) {
            ctrl[CTRL_TE + tc] = e;
            ctrl[CTRL_TR + tc] = off + i * 128;
            tc++;
        }
        off += nt << 7;
    }
    ctrl[CTRL_TOTAL] = tc;
}

// ---------- scatter: fill gathered row info (token idx + combine weight) ----------
__global__ void scatter_kernel(const int* __restrict__ tki, const float* __restrict__ tkw,
                               int* __restrict__ ctrl, int* __restrict__ rit,
                               float* __restrict__ riw) {
    int a = blockIdx.x * 256 + threadIdx.x;
    if (a < 2 * T_TOK) {
        int t = a >> 1;
        int e = tki[a];
        float w = tkw[a];
        int pos = atomicAdd(&ctrl[CTRL_FILL + e], 1);
        int row = ctrl[CTRL_OFFS + e] + pos;
        rit[row] = t; riw[row] = w;
    } else if (a < 3 * T_TOK) {
        int t = a - 2 * T_TOK;
        int row = ctrl[CTRL_OFFS + 16] + t;
        rit[row] = t; riw[row] = 1.0f;
    }
}

// ---------- GEMM1: act = silu(xg @ W1g) * (xg @ W1u), bf16 out ----------
__global__ __launch_bounds__(256, 2)
void gemm1_kernel(const unsigned short* __restrict__ xb,
                  const unsigned short* __restrict__ wt1,
                  const unsigned short* __restrict__ ws1t,
                  unsigned short* __restrict__ hidden,
                  const int* __restrict__ rit,
                  const int* __restrict__ ctrl) {
    __shared__ float ldsf[16896];                 // 67584 B: staging (32KB) U C-scratch (66KB)
    const int tile = blockIdx.x;
    if (tile >= ctrl[CTRL_TOTAL]) return;
    const int e    = ctrl[CTRL_TE + tile];
    const int row0 = ctrl[CTRL_TR + tile];
    const int n0   = blockIdx.y * 64;             // act column base
    const unsigned short* bt = (e < 16) ? (wt1 + (size_t)e * N1 * H_DIM) : ws1t;

    unsigned short* sA = (unsigned short*)ldsf;   // [128][64] bf16, XOR-swizzled
    unsigned short* sB = sA + 128 * BK;

    const int tid = threadIdx.x;
    const int lane = tid & 63;
    const int w = tid >> 6, wm = w >> 1, wn = w & 1;
    const int l15 = lane & 15;
    const int lk8 = (lane >> 4) * 8;

    // per-thread staging addresses (4 x 16B chunks each for A and B)
    int s_row[4]; int s_swz[4]; size_t a_base[4], b_base[4];
    #pragma unroll
    for (int i = 0; i < 4; i++) {
        int c = tid + 256 * i;
        int row = c >> 3;
        int k8 = (c & 7) * 8;
        s_row[i] = row;
        int byte = row * 128 + k8 * 2;
        s_swz[i] = byte ^ ((row & 7) << 4);
        int token = rit[row0 + row];
        a_base[i] = (size_t)token * H_DIM + k8;
        int gn = (row < 64) ? (n0 + row) : (2048 + n0 + row - 64);  // gate rows | up rows
        b_base[i] = (size_t)gn * H_DIM + k8;
    }

    f32x4 acc[4][4];
    #pragma unroll
    for (int a = 0; a < 4; a++)
        #pragma unroll
        for (int b = 0; b < 4; b++) acc[a][b] = (f32x4){0.f, 0.f, 0.f, 0.f};

    for (int k0 = 0; k0 < H_DIM; k0 += BK) {
        #pragma unroll
        for (int i = 0; i < 4; i++) {
            uint4 va = *(const uint4*)(xb + a_base[i] + k0);
            uint4 vb = *(const uint4*)(bt + b_base[i] + k0);
            *(uint4*)((char*)sA + s_swz[i]) = va;
            *(uint4*)((char*)sB + s_swz[i]) = vb;
        }
        __syncthreads();
        #pragma unroll
        for (int kk = 0; kk < 2; kk++) {
            short8 af[4], bfr[4];
            #pragma unroll
            for (int mi = 0; mi < 4; mi++) {
                int row = wm * 64 + mi * 16 + l15;
                int byte = row * 128 + (kk * 32 + lk8) * 2;
                af[mi] = *(const short8*)((const char*)sA + (byte ^ ((row & 7) << 4)));
            }
            #pragma unroll
            for (int ni = 0; ni < 4; ni++) {
                int row = wn * 64 + ni * 16 + l15;
                int byte = row * 128 + (kk * 32 + lk8) * 2;
                bfr[ni] = *(const short8*)((const char*)sB + (byte ^ ((row & 7) << 4)));
            }
            #pragma unroll
            for (int mi = 0; mi < 4; mi++)
                #pragma unroll
                for (int ni = 0; ni < 4; ni++)
                    acc[mi][ni] = __builtin_amdgcn_mfma_f32_16x16x32_bf16(
                        af[mi], bfr[ni], acc[mi][ni], 0, 0, 0);
        }
        __syncthreads();
    }

    // C -> LDS [128][132] f32 (cols 0..63 = gate, 64..127 = up)
    float* ldsC = ldsf;
    const int crow = (lane >> 4) * 4;
    #pragma unroll
    for (int mi = 0; mi < 4; mi++)
        #pragma unroll
        for (int ni = 0; ni < 4; ni++) {
            int row = wm * 64 + mi * 16 + crow;
            int col = wn * 64 + ni * 16 + l15;
            #pragma unroll
            for (int r = 0; r < 4; r++)
                ldsC[(row + r) * 132 + col] = acc[mi][ni][r];
        }
    __syncthreads();
    #pragma unroll
    for (int i = 0; i < 8; i++) {
        int p = tid + i * 256;
        int row = p >> 4;
        int q = (p & 15) * 4;
        float4 g = *(const float4*)&ldsC[row * 132 + q];
        float4 u = *(const float4*)&ldsC[row * 132 + 64 + q];
        float a0 = g.x / (1.f + __expf(-g.x)) * u.x;
        float a1 = g.y / (1.f + __expf(-g.y)) * u.y;
        float a2 = g.z / (1.f + __expf(-g.z)) * u.z;
        float a3 = g.w / (1.f + __expf(-g.w)) * u.w;
        ushort4 hv;
        hv.x = f2bf(a0); hv.y = f2bf(a1); hv.z = f2bf(a2); hv.w = f2bf(a3);
        *(ushort4*)(hidden + (size_t)(row0 + row) * I_DIM + n0 + q) = hv;
    }
}

// ---------- GEMM2: out[token] += wt * (hidden @ W2) ----------
__global__ __launch_bounds__(256, 2)
void gemm2_kernel(const unsigned short* __restrict__ hidden,
                  const unsigned short* __restrict__ wt2,
                  const unsigned short* __restrict__ ws2t,
                  float* __restrict__ out,
                  const int* __restrict__ rit, const float* __restrict__ riw,
                  const int* __restrict__ ctrl) {
    __shared__ float ldsf[8192];                  // 32KB staging
    const int tile = blockIdx.x;
    if (tile >= ctrl[CTRL_TOTAL]) return;
    const int e    = ctrl[CTRL_TE + tile];
    const int row0 = ctrl[CTRL_TR + tile];
    const int n0   = blockIdx.y * 128;
    const unsigned short* bt = (e < 16) ? (wt2 + (size_t)e * H_DIM * I_DIM) : ws2t;

    unsigned short* sA = (unsigned short*)ldsf;
    unsigned short* sB = sA + 128 * BK;

    const int tid = threadIdx.x;
    const int lane = tid & 63;
    const int w = tid >> 6, wm = w >> 1, wn = w & 1;
    const int l15 = lane & 15;
    const int lk8 = (lane >> 4) * 8;

    int s_swz[4]; size_t a_base[4], b_base[4];
    #pragma unroll
    for (int i = 0; i < 4; i++) {
        int c = tid + 256 * i;
        int row = c >> 3;
        int k8 = (c & 7) * 8;
        int byte = row * 128 + k8 * 2;
        s_swz[i] = byte ^ ((row & 7) << 4);
        a_base[i] = (size_t)(row0 + row) * I_DIM + k8;
        b_base[i] = (size_t)(n0 + row) * I_DIM + k8;
    }

    f32x4 acc[4][4];
    #pragma unroll
    for (int a = 0; a < 4; a++)
        #pragma unroll
        for (int b = 0; b < 4; b++) acc[a][b] = (f32x4){0.f, 0.f, 0.f, 0.f};

    for (int k0 = 0; k0 < I_DIM; k0 += BK) {
        #pragma unroll
        for (int i = 0; i < 4; i++) {
            uint4 va = *(const uint4*)(hidden + a_base[i] + k0);
            uint4 vb = *(const uint4*)(bt + b_base[i] + k0);
            *(uint4*)((char*)sA + s_swz[i]) = va;
            *(uint4*)((char*)sB + s_swz[i]) = vb;
        }
        __syncthreads();
        #pragma unroll
        for (int kk = 0; kk < 2; kk++) {
            short8 af[4], bfr[4];
            #pragma unroll
            for (int mi = 0; mi < 4; mi++) {
                int row = wm * 64 + mi * 16 + l15;
                int byte = row * 128 + (kk * 32 + lk8) * 2;
                af[mi] = *(const short8*)((const char*)sA + (byte ^ ((row & 7) << 4)));
            }
            #pragma unroll
            for (int ni = 0; ni < 4; ni++) {
                int row = wn * 64 + ni * 16 + l15;
                int byte = row * 128 + (kk * 32 + lk8) * 2;
                bfr[ni] = *(const short8*)((const char*)sB + (byte ^ ((row & 7) << 4)));
            }
            #pragma unroll
            for (int mi = 0; mi < 4; mi++)
                #pragma unroll
                for (int ni = 0; ni < 4; ni++)
                    acc[mi][ni] = __builtin_amdgcn_mfma_f32_16x16x32_bf16(
                        af[mi], bfr[ni], acc[mi][ni], 0, 0, 0);
        }
        __syncthreads();
    }

    const int crow = (lane >> 4) * 4;
    #pragma unroll
    for (int mi = 0; mi < 4; mi++) {
        int rowb = wm * 64 + mi * 16 + crow;
        #pragma unroll
        for (int r = 0; r < 4; r++) {
            int grow = row0 + rowb + r;
            int token = rit[grow];
            float wt = riw[grow];
            if (wt != 0.0f) {
                float* op = out + (size_t)token * H_DIM + n0;
                #pragma unroll
                for (int ni = 0; ni < 4; ni++) {
                    int col = wn * 64 + ni * 16 + l15;
                    atomicAdd(op + col, wt * acc[mi][ni][r]);
                }
            }
        }
    }
}

extern "C" void kernel_launch(void* const* d_in, const int* in_sizes, int n_in,
                              void* d_out, int out_size, void* d_ws, size_t ws_size,
                              hipStream_t stream) {
    const float* x      = (const float*)d_in[0];
    const float* gate_w = (const float*)d_in[1];
    const float* w1     = (const float*)d_in[2];
    const float* w2     = (const float*)d_in[3];
    const float* ws1    = (const float*)d_in[4];
    const float* ws2    = (const float*)d_in[5];
    float* out = (float*)d_out;
    char* ws = (char*)d_ws;

    unsigned short* wt1  = (unsigned short*)(ws + OFF_WT1);
    unsigned short* wt2  = (unsigned short*)(ws + OFF_WT2);
    unsigned short* ws1t = (unsigned short*)(ws + OFF_WS1T);
    unsigned short* ws2t = (unsigned short*)(ws + OFF_WS2T);
    unsigned short* xb   = (unsigned short*)(ws + OFF_XB);
    unsigned short* hid  = (unsigned short*)(ws + OFF_HID);
    int*   rit  = (int*)(ws + OFF_RIT);
    float* riw  = (float*)(ws + OFF_RIW);
    int*   ctrl = (int*)(ws + OFF_CTRL);
    int*   tki  = (int*)(ws + OFF_TKI);
    float* tkw  = (float*)(ws + OFF_TKW);

    // zero output (routed & shared both atomically accumulate) + control region
    hipMemsetAsync(d_out, 0, (size_t)T_TOK * H_DIM * sizeof(float), stream);
    hipMemsetAsync(ws + OFF_RIT, 0, OFF_TKI - OFF_RIT, stream);

    // weight convert+transpose to bf16 [N][K]
    transpose_cvt_kernel<<<dim3(N1 / 64, H_DIM / 64, E_NUM), 256, 0, stream>>>(w1, wt1, H_DIM, N1);
    transpose_cvt_kernel<<<dim3(H_DIM / 64, I_DIM / 64, E_NUM), 256, 0, stream>>>(w2, wt2, I_DIM, H_DIM);
    transpose_cvt_kernel<<<dim3(N1 / 64, H_DIM / 64, 1), 256, 0, stream>>>(ws1, ws1t, H_DIM, N1);
    transpose_cvt_kernel<<<dim3(H_DIM / 64, I_DIM / 64, 1), 256, 0, stream>>>(ws2, ws2t, I_DIM, H_DIM);
    cvt_x_kernel<<<(T_TOK * H_DIM / 8) / 256, 256, 0, stream>>>(x, xb);

    // routing
    router_kernel<<<T_TOK, 64, 0, stream>>>(x, gate_w, tki, tkw, ctrl);
    prefix_kernel<<<1, 64, 0, stream>>>(ctrl);
    scatter_kernel<<<(3 * T_TOK + 255) / 256, 256, 0, stream>>>(tki, tkw, ctrl, rit, riw);

    // expert MLPs (shared expert folded in as expert 16)
    gemm1_kernel<<<dim3(MAX_TILES, N1 / 2 / 64), 256, 0, stream>>>(xb, wt1, ws1t, hid, rit, ctrl);
    gemm2_kernel<<<dim3(MAX_TILES, H_DIM / 128), 256, 0, stream>>>(hid, wt2, ws2t, out, rit, riw, ctrl);
}

// Round 3
// 1251.699 us; speedup vs baseline: 1.0823x; 1.0823x over previous
//
#include <hip/hip_runtime.h>

#define T_TOK 8192
#define H_DIM 1024
#define E_NUM 16
#define I_DIM 2048
#define N1    4096
#define BK    64
#define MAX_TILES 208
#define MAX_ROWS (MAX_TILES * 128)
#define YB1   32
#define YB2   8

// ctrl layout (int32 indices)
#define CTRL_COUNTS 0
#define CTRL_FILL   32
#define CTRL_OFFS   64
#define CTRL_TOTAL  96
#define CTRL_TE     128
#define CTRL_TR     (128 + MAX_TILES)
#define CTRL_INTS   (128 + 2 * MAX_TILES)

typedef __attribute__((ext_vector_type(8))) short short8;
typedef __attribute__((ext_vector_type(4))) float f32x4;

// ---- workspace layout (bytes) ----
static const size_t OFF_WT1  = 0;                                          // [16][4096][1024] bf16
static const size_t OFF_WT2  = OFF_WT1  + (size_t)E_NUM * N1 * H_DIM * 2;  // [16][1024][2048] bf16
static const size_t OFF_WS1T = OFF_WT2  + (size_t)E_NUM * H_DIM * I_DIM * 2; // [4096][1024]
static const size_t OFF_WS2T = OFF_WS1T + (size_t)N1 * H_DIM * 2;          // [1024][2048]
static const size_t OFF_XB   = OFF_WS2T + (size_t)I_DIM * H_DIM * 2;       // [8192][1024] bf16
static const size_t OFF_HID  = OFF_XB   + (size_t)T_TOK * H_DIM * 2;       // [MAX_ROWS][2048] bf16
static const size_t OFF_RIT  = OFF_HID  + (size_t)MAX_ROWS * I_DIM * 2;    // int[MAX_ROWS]
static const size_t OFF_RIW  = OFF_RIT  + (size_t)MAX_ROWS * 4;            // float[MAX_ROWS]
static const size_t OFF_CTRL = OFF_RIW  + (size_t)MAX_ROWS * 4;            // int[CTRL_INTS]
static const size_t OFF_TKI  = OFF_CTRL + (size_t)CTRL_INTS * 4;           // int[T][2]
static const size_t OFF_TKW  = OFF_TKI  + (size_t)T_TOK * 2 * 4;           // float[T][2]

__device__ __forceinline__ unsigned short f2bf(float f) {
    unsigned int u = __float_as_uint(f);
    u = (u + 0x7FFFu + ((u >> 16) & 1u)) >> 16;   // RNE
    return (unsigned short)u;
}

typedef __attribute__((address_space(1))) const void gv1_t;
typedef __attribute__((address_space(3))) void lv3_t;
__device__ __forceinline__ void gload16(const void* g, void* l) {
    // width-16 global->LDS DMA; LDS dest = wave-uniform base + lane*16
    __builtin_amdgcn_global_load_lds((gv1_t*)g, (lv3_t*)l, 16, 0, 0);
}

// ---------- transpose + f32->bf16: dst[b][c][r] = bf16(src[b][r][c]) ----------
__global__ void transpose_cvt_kernel(const float* __restrict__ src,
                                     unsigned short* __restrict__ dst,
                                     int R, int C) {
    __shared__ float tile[64][65];
    const size_t base = (size_t)blockIdx.z * R * C;
    const int c0 = blockIdx.x * 64, r0 = blockIdx.y * 64;
    const int tid = threadIdx.x;
    const int lr = tid >> 4;            // 0..15
    const int lc = (tid & 15) * 4;      // 0..60
    #pragma unroll
    for (int i = 0; i < 4; i++) {
        int r = lr + i * 16;
        float4 v = *(const float4*)&src[base + (size_t)(r0 + r) * C + (c0 + lc)];
        tile[r][lc] = v.x; tile[r][lc + 1] = v.y; tile[r][lc + 2] = v.z; tile[r][lc + 3] = v.w;
    }
    __syncthreads();
    #pragma unroll
    for (int i = 0; i < 2; i++) {
        int p = tid + i * 256;
        int c = p >> 3;                 // 0..63
        int r8 = (p & 7) * 8;           // 0..56
        unsigned int h[8];
        #pragma unroll
        for (int j = 0; j < 8; j++) h[j] = f2bf(tile[r8 + j][c]);
        uint4 o;
        o.x = h[0] | (h[1] << 16); o.y = h[2] | (h[3] << 16);
        o.z = h[4] | (h[5] << 16); o.w = h[6] | (h[7] << 16);
        *(uint4*)(dst + base + (size_t)(c0 + c) * R + (r0 + r8)) = o;
    }
}

// ---------- x f32 -> bf16 ----------
__global__ void cvt_x_kernel(const float* __restrict__ x, unsigned short* __restrict__ xb) {
    size_t i = (size_t)blockIdx.x * 256 + threadIdx.x;
    const float4* xp = (const float4*)x;
    float4 v0 = xp[i * 2], v1 = xp[i * 2 + 1];
    uint4 o;
    o.x = (unsigned)f2bf(v0.x) | ((unsigned)f2bf(v0.y) << 16);
    o.y = (unsigned)f2bf(v0.z) | ((unsigned)f2bf(v0.w) << 16);
    o.z = (unsigned)f2bf(v1.x) | ((unsigned)f2bf(v1.y) << 16);
    o.w = (unsigned)f2bf(v1.z) | ((unsigned)f2bf(v1.w) << 16);
    ((uint4*)xb)[i] = o;
}

// ---------- router ----------
__global__ void router_kernel(const float* __restrict__ x, const float* __restrict__ gw,
                              int* __restrict__ tki, float* __restrict__ tkw,
                              int* __restrict__ ctrl) {
    const int t = blockIdx.x;
    const int lane = threadIdx.x;
    float acc[16];
    #pragma unroll
    for (int e = 0; e < 16; e++) acc[e] = 0.f;
    const float* xr = x + (size_t)t * H_DIM;
    for (int h = lane; h < H_DIM; h += 64) {
        float xv = xr[h];
        const float4* g4 = (const float4*)(gw + h * 16);
        float4 a = g4[0], b = g4[1], c = g4[2], d = g4[3];
        acc[0] += xv * a.x; acc[1] += xv * a.y; acc[2]  += xv * a.z; acc[3]  += xv * a.w;
        acc[4] += xv * b.x; acc[5] += xv * b.y; acc[6]  += xv * b.z; acc[7]  += xv * b.w;
        acc[8] += xv * c.x; acc[9] += xv * c.y; acc[10] += xv * c.z; acc[11] += xv * c.w;
        acc[12]+= xv * d.x; acc[13]+= xv * d.y; acc[14] += xv * d.z; acc[15] += xv * d.w;
    }
    #pragma unroll
    for (int e = 0; e < 16; e++) {
        #pragma unroll
        for (int s = 32; s > 0; s >>= 1) acc[e] += __shfl_xor(acc[e], s);
    }
    if (lane == 0) {
        float sc[16];
        #pragma unroll
        for (int e = 0; e < 16; e++) sc[e] = 1.f / (1.f + __expf(-acc[e]));
        int i1 = 0;
        #pragma unroll
        for (int e = 1; e < 16; e++) if (sc[e] > sc[i1]) i1 = e;
        int i2 = (i1 == 0) ? 1 : 0;
        #pragma unroll
        for (int e = 0; e < 16; e++) if (e != i1 && sc[e] > sc[i2]) i2 = e;
        float s = sc[i1] + sc[i2];
        tki[2 * t] = i1; tki[2 * t + 1] = i2;
        tkw[2 * t] = sc[i1] / s; tkw[2 * t + 1] = sc[i2] / s;
        atomicAdd(&ctrl[CTRL_COUNTS + i1], 1);
        atomicAdd(&ctrl[CTRL_COUNTS + i2], 1);
    }
}

// ---------- prefix ----------
__global__ void prefix_kernel(int* __restrict__ ctrl) {
    if (threadIdx.x != 0) return;
    int off = 0, tc = 0;
    for (int e = 0; e <= 16; e++) {
        int c = (e == 16) ? T_TOK : ctrl[CTRL_COUNTS + e];
        ctrl[CTRL_OFFS + e] = off;
        int nt = (c + 127) >> 7;
        for (int i = 0; i < nt; i++) {
            ctrl[CTRL_TE + tc] = e;
            ctrl[CTRL_TR + tc] = off + i * 128;
            tc++;
        }
        off += nt << 7;
    }
    ctrl[CTRL_TOTAL] = tc;
}

// ---------- scatter ----------
__global__ void scatter_kernel(const int* __restrict__ tki, const float* __restrict__ tkw,
                               int* __restrict__ ctrl, int* __restrict__ rit,
                               float* __restrict__ riw) {
    int a = blockIdx.x * 256 + threadIdx.x;
    if (a < 2 * T_TOK) {
        int t = a >> 1;
        int e = tki[a];
        float w = tkw[a];
        int pos = atomicAdd(&ctrl[CTRL_FILL + e], 1);
        int row = ctrl[CTRL_OFFS + e] + pos;
        rit[row] = t; riw[row] = w;
    } else if (a < 3 * T_TOK) {
        int t = a - 2 * T_TOK;
        int row = ctrl[CTRL_OFFS + 16] + t;
        rit[row] = t; riw[row] = 1.0f;
    }
}

// XCD-bijective chunk swizzle over the live block range (m204)
__device__ __forceinline__ int xcd_swz(int id, int live) {
    int xcd = id & 7, off = id >> 3;
    int q = live >> 3, rr = live & 7;
    return (xcd < rr ? xcd * (q + 1) : rr * (q + 1) + (xcd - rr) * q) + off;
}

// ---------- GEMM1: hidden = silu(x@W1g)*(x@W1u), bf16 out ----------
// B LDS row r (0..127): half=(r>>4)&1 (0=gate,1=up), colgroup=r>>5, col=n0+cg*16+(r&15)
__global__ __launch_bounds__(256, 2)
void gemm1_kernel(const unsigned short* __restrict__ xb,
                  const unsigned short* __restrict__ wt1,
                  const unsigned short* __restrict__ ws1t,
                  unsigned short* __restrict__ hidden,
                  const int* __restrict__ rit,
                  const int* __restrict__ ctrl) {
    __shared__ unsigned short sA[128 * BK];   // [128 rows][64 k] linear
    __shared__ unsigned short sB[128 * BK];
    const int total = ctrl[CTRL_TOTAL];
    const int live = total * YB1;
    int id = blockIdx.x;
    if (id >= live) return;
    id = xcd_swz(id, live);
    const int tile = id >> 5;            // /YB1
    const int n0 = (id & 31) * 64;
    const int e    = ctrl[CTRL_TE + tile];
    const int row0 = ctrl[CTRL_TR + tile];
    const unsigned short* bt = (e < 16) ? (wt1 + (size_t)e * N1 * H_DIM) : ws1t;

    const int tid = threadIdx.x;
    const int lane = tid & 63;
    const int w = tid >> 6, wm = w >> 1, wn = w & 1;
    const int l15 = lane & 15;
    const int lk8 = (lane >> 4) * 8;
    const int k8 = (tid & 7) * 8;

    const unsigned short* gA[4];
    const unsigned short* gB[4];
    #pragma unroll
    for (int i = 0; i < 4; i++) {
        int r = i * 32 + (tid >> 3);
        gA[i] = xb + (size_t)rit[row0 + r] * H_DIM + k8;
        int half = (r >> 4) & 1, cg = r >> 5;
        int gn = half * I_DIM + n0 + cg * 16 + (r & 15);
        gB[i] = bt + (size_t)gn * H_DIM + k8;
    }
    char* lA = (char*)sA + (tid & 192) * 16;   // wave-uniform base
    char* lB = (char*)sB + (tid & 192) * 16;

    f32x4 acc[4][4];
    #pragma unroll
    for (int a = 0; a < 4; a++)
        #pragma unroll
        for (int b = 0; b < 4; b++) acc[a][b] = (f32x4){0.f, 0.f, 0.f, 0.f};

    for (int k0 = 0; k0 < H_DIM; k0 += BK) {
        #pragma unroll
        for (int i = 0; i < 4; i++) gload16(gA[i] + k0, lA + i * 4096);
        #pragma unroll
        for (int i = 0; i < 4; i++) gload16(gB[i] + k0, lB + i * 4096);
        __syncthreads();
        #pragma unroll
        for (int kk = 0; kk < 2; kk++) {
            short8 af[4], bfr[4];
            #pragma unroll
            for (int mi = 0; mi < 4; mi++)
                af[mi] = *(const short8*)((const char*)sA +
                          (wm * 64 + mi * 16 + l15) * 128 + kk * 64 + lk8 * 2);
            #pragma unroll
            for (int ni = 0; ni < 4; ni++)
                bfr[ni] = *(const short8*)((const char*)sB +
                          (wn * 64 + ni * 16 + l15) * 128 + kk * 64 + lk8 * 2);
            #pragma unroll
            for (int mi = 0; mi < 4; mi++)
                #pragma unroll
                for (int ni = 0; ni < 4; ni++)
                    acc[mi][ni] = __builtin_amdgcn_mfma_f32_16x16x32_bf16(
                        af[mi], bfr[ni], acc[mi][ni], 0, 0, 0);
        }
        __syncthreads();
    }

    // epilogue in registers: ni=2p gate, ni=2p+1 up of cols n0+(wn*2+p)*16+l15
    const int crow = (lane >> 4) * 4;
    #pragma unroll
    for (int mi = 0; mi < 4; mi++) {
        int rowb = row0 + wm * 64 + mi * 16 + crow;
        #pragma unroll
        for (int p = 0; p < 2; p++) {
            int col = n0 + (wn * 2 + p) * 16 + l15;
            f32x4 g = acc[mi][2 * p], u = acc[mi][2 * p + 1];
            #pragma unroll
            for (int r = 0; r < 4; r++) {
                float gv = g[r];
                float val = gv / (1.f + __expf(-gv)) * u[r];
                hidden[(size_t)(rowb + r) * I_DIM + col] = f2bf(val);
            }
        }
    }
}

// ---------- GEMM2: out[token] += wt * (hidden @ W2) ----------
__global__ __launch_bounds__(256, 2)
void gemm2_kernel(const unsigned short* __restrict__ hidden,
                  const unsigned short* __restrict__ wt2,
                  const unsigned short* __restrict__ ws2t,
                  float* __restrict__ out,
                  const int* __restrict__ rit, const float* __restrict__ riw,
                  const int* __restrict__ ctrl) {
    __shared__ unsigned short sA[128 * BK];
    __shared__ unsigned short sB[128 * BK];
    const int total = ctrl[CTRL_TOTAL];
    const int live = total * YB2;
    int id = blockIdx.x;
    if (id >= live) return;
    id = xcd_swz(id, live);
    const int tile = id >> 3;
    const int n0 = (id & 7) * 128;
    const int e    = ctrl[CTRL_TE + tile];
    const int row0 = ctrl[CTRL_TR + tile];
    const unsigned short* bt = (e < 16) ? (wt2 + (size_t)e * H_DIM * I_DIM) : ws2t;

    const int tid = threadIdx.x;
    const int lane = tid & 63;
    const int w = tid >> 6, wm = w >> 1, wn = w & 1;
    const int l15 = lane & 15;
    const int lk8 = (lane >> 4) * 8;
    const int k8 = (tid & 7) * 8;

    const unsigned short* gA[4];
    const unsigned short* gB[4];
    #pragma unroll
    for (int i = 0; i < 4; i++) {
        int r = i * 32 + (tid >> 3);
        gA[i] = hidden + (size_t)(row0 + r) * I_DIM + k8;
        gB[i] = bt + (size_t)(n0 + r) * I_DIM + k8;
    }
    char* lA = (char*)sA + (tid & 192) * 16;
    char* lB = (char*)sB + (tid & 192) * 16;

    f32x4 acc[4][4];
    #pragma unroll
    for (int a = 0; a < 4; a++)
        #pragma unroll
        for (int b = 0; b < 4; b++) acc[a][b] = (f32x4){0.f, 0.f, 0.f, 0.f};

    for (int k0 = 0; k0 < I_DIM; k0 += BK) {
        #pragma unroll
        for (int i = 0; i < 4; i++) gload16(gA[i] + k0, lA + i * 4096);
        #pragma unroll
        for (int i = 0; i < 4; i++) gload16(gB[i] + k0, lB + i * 4096);
        __syncthreads();
        #pragma unroll
        for (int kk = 0; kk < 2; kk++) {
            short8 af[4], bfr[4];
            #pragma unroll
            for (int mi = 0; mi < 4; mi++)
                af[mi] = *(const short8*)((const char*)sA +
                          (wm * 64 + mi * 16 + l15) * 128 + kk * 64 + lk8 * 2);
            #pragma unroll
            for (int ni = 0; ni < 4; ni++)
                bfr[ni] = *(const short8*)((const char*)sB +
                          (wn * 64 + ni * 16 + l15) * 128 + kk * 64 + lk8 * 2);
            #pragma unroll
            for (int mi = 0; mi < 4; mi++)
                #pragma unroll
                for (int ni = 0; ni < 4; ni++)
                    acc[mi][ni] = __builtin_amdgcn_mfma_f32_16x16x32_bf16(
                        af[mi], bfr[ni], acc[mi][ni], 0, 0, 0);
        }
        __syncthreads();
    }

    const int crow = (lane >> 4) * 4;
    #pragma unroll
    for (int mi = 0; mi < 4; mi++) {
        int rowb = wm * 64 + mi * 16 + crow;
        #pragma unroll
        for (int r = 0; r < 4; r++) {
            int grow = row0 + rowb + r;
            int token = rit[grow];
            float wt = riw[grow];
            if (wt != 0.0f) {
                float* op = out + (size_t)token * H_DIM + n0;
                #pragma unroll
                for (int ni = 0; ni < 4; ni++) {
                    int col = wn * 64 + ni * 16 + l15;
                    atomicAdd(op + col, wt * acc[mi][ni][r]);
                }
            }
        }
    }
}

extern "C" void kernel_launch(void* const* d_in, const int* in_sizes, int n_in,
                              void* d_out, int out_size, void* d_ws, size_t ws_size,
                              hipStream_t stream) {
    const float* x      = (const float*)d_in[0];
    const float* gate_w = (const float*)d_in[1];
    const float* w1     = (const float*)d_in[2];
    const float* w2     = (const float*)d_in[3];
    const float* ws1    = (const float*)d_in[4];
    const float* ws2    = (const float*)d_in[5];
    float* out = (float*)d_out;
    char* ws = (char*)d_ws;

    unsigned short* wt1  = (unsigned short*)(ws + OFF_WT1);
    unsigned short* wt2  = (unsigned short*)(ws + OFF_WT2);
    unsigned short* ws1t = (unsigned short*)(ws + OFF_WS1T);
    unsigned short* ws2t = (unsigned short*)(ws + OFF_WS2T);
    unsigned short* xb   = (unsigned short*)(ws + OFF_XB);
    unsigned short* hid  = (unsigned short*)(ws + OFF_HID);
    int*   rit  = (int*)(ws + OFF_RIT);
    float* riw  = (float*)(ws + OFF_RIW);
    int*   ctrl = (int*)(ws + OFF_CTRL);
    int*   tki  = (int*)(ws + OFF_TKI);
    float* tkw  = (float*)(ws + OFF_TKW);

    hipMemsetAsync(d_out, 0, (size_t)T_TOK * H_DIM * sizeof(float), stream);
    hipMemsetAsync(ws + OFF_RIT, 0, OFF_TKI - OFF_RIT, stream);

    transpose_cvt_kernel<<<dim3(N1 / 64, H_DIM / 64, E_NUM), 256, 0, stream>>>(w1, wt1, H_DIM, N1);
    transpose_cvt_kernel<<<dim3(H_DIM / 64, I_DIM / 64, E_NUM), 256, 0, stream>>>(w2, wt2, I_DIM, H_DIM);
    transpose_cvt_kernel<<<dim3(N1 / 64, H_DIM / 64, 1), 256, 0, stream>>>(ws1, ws1t, H_DIM, N1);
    transpose_cvt_kernel<<<dim3(H_DIM / 64, I_DIM / 64, 1), 256, 0, stream>>>(ws2, ws2t, I_DIM, H_DIM);
    cvt_x_kernel<<<(T_TOK * H_DIM / 8) / 256, 256, 0, stream>>>(x, xb);

    router_kernel<<<T_TOK, 64, 0, stream>>>(x, gate_w, tki, tkw, ctrl);
    prefix_kernel<<<1, 64, 0, stream>>>(ctrl);
    scatter_kernel<<<(3 * T_TOK + 255) / 256, 256, 0, stream>>>(tki, tkw, ctrl, rit, riw);

    gemm1_kernel<<<MAX_TILES * YB1, 256, 0, stream>>>(xb, wt1, ws1t, hid, rit, ctrl);
    gemm2_kernel<<<MAX_TILES * YB2, 256, 0, stream>>>(hid, wt2, ws2t, out, rit, riw, ctrl);
}

// Round 4
// 1211.971 us; speedup vs baseline: 1.1177x; 1.0328x over previous
//
#include <hip/hip_runtime.h>

#define T_TOK 8192
#define H_DIM 1024
#define E_NUM 16
#define I_DIM 2048
#define N1    4096
#define BK    64
#define MAX_TILES 208
#define MAX_ROWS (MAX_TILES * 128)
#define YB1   32
#define YB2   8

// ctrl layout (int32 indices)
#define CTRL_COUNTS 0
#define CTRL_FILL   32
#define CTRL_OFFS   64
#define CTRL_TOTAL  96
#define CTRL_TE     128
#define CTRL_TR     (128 + MAX_TILES)
#define CTRL_INTS   (128 + 2 * MAX_TILES)

typedef __attribute__((ext_vector_type(8))) short short8;
typedef __attribute__((ext_vector_type(4))) float f32x4;

// ---- workspace layout (bytes) ----
static const size_t OFF_WT1  = 0;                                          // [16][4096][1024] bf16
static const size_t OFF_WT2  = OFF_WT1  + (size_t)E_NUM * N1 * H_DIM * 2;  // [16][1024][2048] bf16
static const size_t OFF_WS1T = OFF_WT2  + (size_t)E_NUM * H_DIM * I_DIM * 2; // [4096][1024]
static const size_t OFF_WS2T = OFF_WS1T + (size_t)N1 * H_DIM * 2;          // [1024][2048]
static const size_t OFF_XB   = OFF_WS2T + (size_t)I_DIM * H_DIM * 2;       // [8192][1024] bf16
static const size_t OFF_HID  = OFF_XB   + (size_t)T_TOK * H_DIM * 2;       // [MAX_ROWS][2048] bf16
static const size_t OFF_RIT  = OFF_HID  + (size_t)MAX_ROWS * I_DIM * 2;    // int[MAX_ROWS]
static const size_t OFF_RIW  = OFF_RIT  + (size_t)MAX_ROWS * 4;            // float[MAX_ROWS]
static const size_t OFF_CTRL = OFF_RIW  + (size_t)MAX_ROWS * 4;            // int[CTRL_INTS]
static const size_t OFF_TKI  = OFF_CTRL + (size_t)CTRL_INTS * 4;           // int[T][2]
static const size_t OFF_TKW  = OFF_TKI  + (size_t)T_TOK * 2 * 4;           // float[T][2]

__device__ __forceinline__ unsigned short f2bf(float f) {
    unsigned int u = __float_as_uint(f);
    u = (u + 0x7FFFu + ((u >> 16) & 1u)) >> 16;   // RNE
    return (unsigned short)u;
}

typedef __attribute__((address_space(1))) const void gv1_t;
typedef __attribute__((address_space(3))) void lv3_t;
__device__ __forceinline__ void gload16(const void* g, void* l) {
    // width-16 global->LDS DMA; LDS dest = wave-uniform base + lane*16
    __builtin_amdgcn_global_load_lds((gv1_t*)g, (lv3_t*)l, 16, 0, 0);
}

// ---------- transpose + f32->bf16: dst[b][c][r] = bf16(src[b][r][c]) ----------
__global__ void transpose_cvt_kernel(const float* __restrict__ src,
                                     unsigned short* __restrict__ dst,
                                     int R, int C) {
    __shared__ float tile[64][65];
    const size_t base = (size_t)blockIdx.z * R * C;
    const int c0 = blockIdx.x * 64, r0 = blockIdx.y * 64;
    const int tid = threadIdx.x;
    const int lr = tid >> 4;            // 0..15
    const int lc = (tid & 15) * 4;      // 0..60
    #pragma unroll
    for (int i = 0; i < 4; i++) {
        int r = lr + i * 16;
        float4 v = *(const float4*)&src[base + (size_t)(r0 + r) * C + (c0 + lc)];
        tile[r][lc] = v.x; tile[r][lc + 1] = v.y; tile[r][lc + 2] = v.z; tile[r][lc + 3] = v.w;
    }
    __syncthreads();
    #pragma unroll
    for (int i = 0; i < 2; i++) {
        int p = tid + i * 256;
        int c = p >> 3;                 // 0..63
        int r8 = (p & 7) * 8;           // 0..56
        unsigned int h[8];
        #pragma unroll
        for (int j = 0; j < 8; j++) h[j] = f2bf(tile[r8 + j][c]);
        uint4 o;
        o.x = h[0] | (h[1] << 16); o.y = h[2] | (h[3] << 16);
        o.z = h[4] | (h[5] << 16); o.w = h[6] | (h[7] << 16);
        *(uint4*)(dst + base + (size_t)(c0 + c) * R + (r0 + r8)) = o;
    }
}

// ---------- x f32 -> bf16 ----------
__global__ void cvt_x_kernel(const float* __restrict__ x, unsigned short* __restrict__ xb) {
    size_t i = (size_t)blockIdx.x * 256 + threadIdx.x;
    const float4* xp = (const float4*)x;
    float4 v0 = xp[i * 2], v1 = xp[i * 2 + 1];
    uint4 o;
    o.x = (unsigned)f2bf(v0.x) | ((unsigned)f2bf(v0.y) << 16);
    o.y = (unsigned)f2bf(v0.z) | ((unsigned)f2bf(v0.w) << 16);
    o.z = (unsigned)f2bf(v1.x) | ((unsigned)f2bf(v1.y) << 16);
    o.w = (unsigned)f2bf(v1.z) | ((unsigned)f2bf(v1.w) << 16);
    ((uint4*)xb)[i] = o;
}

// ---------- router ----------
__global__ void router_kernel(const float* __restrict__ x, const float* __restrict__ gw,
                              int* __restrict__ tki, float* __restrict__ tkw,
                              int* __restrict__ ctrl) {
    const int t = blockIdx.x;
    const int lane = threadIdx.x;
    float acc[16];
    #pragma unroll
    for (int e = 0; e < 16; e++) acc[e] = 0.f;
    const float* xr = x + (size_t)t * H_DIM;
    for (int h = lane; h < H_DIM; h += 64) {
        float xv = xr[h];
        const float4* g4 = (const float4*)(gw + h * 16);
        float4 a = g4[0], b = g4[1], c = g4[2], d = g4[3];
        acc[0] += xv * a.x; acc[1] += xv * a.y; acc[2]  += xv * a.z; acc[3]  += xv * a.w;
        acc[4] += xv * b.x; acc[5] += xv * b.y; acc[6]  += xv * b.z; acc[7]  += xv * b.w;
        acc[8] += xv * c.x; acc[9] += xv * c.y; acc[10] += xv * c.z; acc[11] += xv * c.w;
        acc[12]+= xv * d.x; acc[13]+= xv * d.y; acc[14] += xv * d.z; acc[15] += xv * d.w;
    }
    #pragma unroll
    for (int e = 0; e < 16; e++) {
        #pragma unroll
        for (int s = 32; s > 0; s >>= 1) acc[e] += __shfl_xor(acc[e], s);
    }
    if (lane == 0) {
        float sc[16];
        #pragma unroll
        for (int e = 0; e < 16; e++) sc[e] = 1.f / (1.f + __expf(-acc[e]));
        int i1 = 0;
        #pragma unroll
        for (int e = 1; e < 16; e++) if (sc[e] > sc[i1]) i1 = e;
        int i2 = (i1 == 0) ? 1 : 0;
        #pragma unroll
        for (int e = 0; e < 16; e++) if (e != i1 && sc[e] > sc[i2]) i2 = e;
        float s = sc[i1] + sc[i2];
        tki[2 * t] = i1; tki[2 * t + 1] = i2;
        tkw[2 * t] = sc[i1] / s; tkw[2 * t + 1] = sc[i2] / s;
        atomicAdd(&ctrl[CTRL_COUNTS + i1], 1);
        atomicAdd(&ctrl[CTRL_COUNTS + i2], 1);
    }
}

// ---------- prefix ----------
__global__ void prefix_kernel(int* __restrict__ ctrl) {
    if (threadIdx.x != 0) return;
    int off = 0, tc = 0;
    for (int e = 0; e <= 16; e++) {
        int c = (e == 16) ? T_TOK : ctrl[CTRL_COUNTS + e];
        ctrl[CTRL_OFFS + e] = off;
        int nt = (c + 127) >> 7;
        for (int i = 0; i < nt; i++) {
            ctrl[CTRL_TE + tc] = e;
            ctrl[CTRL_TR + tc] = off + i * 128;
            tc++;
        }
        off += nt << 7;
    }
    ctrl[CTRL_TOTAL] = tc;
}

// ---------- scatter ----------
__global__ void scatter_kernel(const int* __restrict__ tki, const float* __restrict__ tkw,
                               int* __restrict__ ctrl, int* __restrict__ rit,
                               float* __restrict__ riw) {
    int a = blockIdx.x * 256 + threadIdx.x;
    if (a < 2 * T_TOK) {
        int t = a >> 1;
        int e = tki[a];
        float w = tkw[a];
        int pos = atomicAdd(&ctrl[CTRL_FILL + e], 1);
        int row = ctrl[CTRL_OFFS + e] + pos;
        rit[row] = t; riw[row] = w;
    } else if (a < 3 * T_TOK) {
        int t = a - 2 * T_TOK;
        int row = ctrl[CTRL_OFFS + 16] + t;
        rit[row] = t; riw[row] = 1.0f;
    }
}

// XCD-bijective chunk swizzle over the live block range (m204)
__device__ __forceinline__ int xcd_swz(int id, int live) {
    int xcd = id & 7, off = id >> 3;
    int q = live >> 3, rr = live & 7;
    return (xcd < rr ? xcd * (q + 1) : rr * (q + 1) + (xcd - rr) * q) + off;
}

// ---------- GEMM1: hidden = silu(x@W1g)*(x@W1u), bf16 out ----------
// work id = n0idx * total + tile  (n0 outer: B-slice L2-reuse across same-expert tiles)
// B LDS row r (0..127): half=(r>>4)&1 (0=gate,1=up), colgroup=r>>5, col=n0+cg*16+(r&15)
// LDS both-sides swizzle: linear DMA dest + source chunk ^(row&7) + read ^((row&7)<<4)
__global__ __launch_bounds__(256, 2)
void gemm1_kernel(const unsigned short* __restrict__ xb,
                  const unsigned short* __restrict__ wt1,
                  const unsigned short* __restrict__ ws1t,
                  unsigned short* __restrict__ hidden,
                  const int* __restrict__ rit,
                  const int* __restrict__ ctrl) {
    __shared__ unsigned short sA[128 * BK];   // [128 rows][64 k] swizzled
    __shared__ unsigned short sB[128 * BK];
    const int total = ctrl[CTRL_TOTAL];
    const int live = total * YB1;
    int id = blockIdx.x;
    if (id >= live) return;
    id = xcd_swz(id, live);
    const int tile = id % total;
    const int n0 = (id / total) * 64;
    const int e    = ctrl[CTRL_TE + tile];
    const int row0 = ctrl[CTRL_TR + tile];
    const unsigned short* bt = (e < 16) ? (wt1 + (size_t)e * N1 * H_DIM) : ws1t;

    const int tid = threadIdx.x;
    const int lane = tid & 63;
    const int w = tid >> 6, wm = w >> 1, wn = w & 1;
    const int l15 = lane & 15;
    const int lk8 = (lane >> 4) * 8;
    // swizzled source k-chunk: chunk j0=tid&7 at row r holds data chunk j0^(r&7)
    const int k8s = (((tid & 7) ^ ((tid >> 3) & 7))) * 8;

    const unsigned short* gA[4];
    const unsigned short* gB[4];
    #pragma unroll
    for (int i = 0; i < 4; i++) {
        int r = i * 32 + (tid >> 3);
        gA[i] = xb + (size_t)rit[row0 + r] * H_DIM + k8s;
        int half = (r >> 4) & 1, cg = r >> 5;
        int gn = half * I_DIM + n0 + cg * 16 + (r & 15);
        gB[i] = bt + (size_t)gn * H_DIM + k8s;
    }
    char* lA = (char*)sA + (tid & 192) * 16;   // wave-uniform base
    char* lB = (char*)sB + (tid & 192) * 16;

    const int rswz = (l15 & 7) << 4;           // read-side XOR (row&7 == l15&7)

    f32x4 acc[4][4];
    #pragma unroll
    for (int a = 0; a < 4; a++)
        #pragma unroll
        for (int b = 0; b < 4; b++) acc[a][b] = (f32x4){0.f, 0.f, 0.f, 0.f};

    for (int k0 = 0; k0 < H_DIM; k0 += BK) {
        #pragma unroll
        for (int i = 0; i < 4; i++) gload16(gA[i] + k0, lA + i * 4096);
        #pragma unroll
        for (int i = 0; i < 4; i++) gload16(gB[i] + k0, lB + i * 4096);
        __syncthreads();
        #pragma unroll
        for (int kk = 0; kk < 2; kk++) {
            short8 af[4], bfr[4];
            #pragma unroll
            for (int mi = 0; mi < 4; mi++)
                af[mi] = *(const short8*)((const char*)sA +
                          ((((wm * 64 + mi * 16 + l15) * 128) + kk * 64 + lk8 * 2) ^ rswz));
            #pragma unroll
            for (int ni = 0; ni < 4; ni++)
                bfr[ni] = *(const short8*)((const char*)sB +
                          ((((wn * 64 + ni * 16 + l15) * 128) + kk * 64 + lk8 * 2) ^ rswz));
            #pragma unroll
            for (int mi = 0; mi < 4; mi++)
                #pragma unroll
                for (int ni = 0; ni < 4; ni++)
                    acc[mi][ni] = __builtin_amdgcn_mfma_f32_16x16x32_bf16(
                        af[mi], bfr[ni], acc[mi][ni], 0, 0, 0);
        }
        __syncthreads();
    }

    // epilogue in registers: ni=2p gate, ni=2p+1 up of cols n0+(wn*2+p)*16+l15
    const int crow = (lane >> 4) * 4;
    #pragma unroll
    for (int mi = 0; mi < 4; mi++) {
        int rowb = row0 + wm * 64 + mi * 16 + crow;
        #pragma unroll
        for (int p = 0; p < 2; p++) {
            int col = n0 + (wn * 2 + p) * 16 + l15;
            f32x4 g = acc[mi][2 * p], u = acc[mi][2 * p + 1];
            #pragma unroll
            for (int r = 0; r < 4; r++) {
                float gv = g[r];
                float val = gv / (1.f + __expf(-gv)) * u[r];
                hidden[(size_t)(rowb + r) * I_DIM + col] = f2bf(val);
            }
        }
    }
}

// ---------- GEMM2: out[token] += wt * (hidden @ W2) ----------
__global__ __launch_bounds__(256, 2)
void gemm2_kernel(const unsigned short* __restrict__ hidden,
                  const unsigned short* __restrict__ wt2,
                  const unsigned short* __restrict__ ws2t,
                  float* __restrict__ out,
                  const int* __restrict__ rit, const float* __restrict__ riw,
                  const int* __restrict__ ctrl) {
    __shared__ unsigned short sA[128 * BK];
    __shared__ unsigned short sB[128 * BK];
    const int total = ctrl[CTRL_TOTAL];
    const int live = total * YB2;
    int id = blockIdx.x;
    if (id >= live) return;
    id = xcd_swz(id, live);
    const int tile = id >> 3;
    const int n0 = (id & 7) * 128;
    const int e    = ctrl[CTRL_TE + tile];
    const int row0 = ctrl[CTRL_TR + tile];
    const unsigned short* bt = (e < 16) ? (wt2 + (size_t)e * H_DIM * I_DIM) : ws2t;

    const int tid = threadIdx.x;
    const int lane = tid & 63;
    const int w = tid >> 6, wm = w >> 1, wn = w & 1;
    const int l15 = lane & 15;
    const int lk8 = (lane >> 4) * 8;
    const int k8s = (((tid & 7) ^ ((tid >> 3) & 7))) * 8;

    const unsigned short* gA[4];
    const unsigned short* gB[4];
    #pragma unroll
    for (int i = 0; i < 4; i++) {
        int r = i * 32 + (tid >> 3);
        gA[i] = hidden + (size_t)(row0 + r) * I_DIM + k8s;
        gB[i] = bt + (size_t)(n0 + r) * I_DIM + k8s;
    }
    char* lA = (char*)sA + (tid & 192) * 16;
    char* lB = (char*)sB + (tid & 192) * 16;

    const int rswz = (l15 & 7) << 4;

    f32x4 acc[4][4];
    #pragma unroll
    for (int a = 0; a < 4; a++)
        #pragma unroll
        for (int b = 0; b < 4; b++) acc[a][b] = (f32x4){0.f, 0.f, 0.f, 0.f};

    for (int k0 = 0; k0 < I_DIM; k0 += BK) {
        #pragma unroll
        for (int i = 0; i < 4; i++) gload16(gA[i] + k0, lA + i * 4096);
        #pragma unroll
        for (int i = 0; i < 4; i++) gload16(gB[i] + k0, lB + i * 4096);
        __syncthreads();
        #pragma unroll
        for (int kk = 0; kk < 2; kk++) {
            short8 af[4], bfr[4];
            #pragma unroll
            for (int mi = 0; mi < 4; mi++)
                af[mi] = *(const short8*)((const char*)sA +
                          ((((wm * 64 + mi * 16 + l15) * 128) + kk * 64 + lk8 * 2) ^ rswz));
            #pragma unroll
            for (int ni = 0; ni < 4; ni++)
                bfr[ni] = *(const short8*)((const char*)sB +
                          ((((wn * 64 + ni * 16 + l15) * 128) + kk * 64 + lk8 * 2) ^ rswz));
            #pragma unroll
            for (int mi = 0; mi < 4; mi++)
                #pragma unroll
                for (int ni = 0; ni < 4; ni++)
                    acc[mi][ni] = __builtin_amdgcn_mfma_f32_16x16x32_bf16(
                        af[mi], bfr[ni], acc[mi][ni], 0, 0, 0);
        }
        __syncthreads();
    }

    const int crow = (lane >> 4) * 4;
    #pragma unroll
    for (int mi = 0; mi < 4; mi++) {
        int rowb = wm * 64 + mi * 16 + crow;
        #pragma unroll
        for (int r = 0; r < 4; r++) {
            int grow = row0 + rowb + r;
            int token = rit[grow];
            float wt = riw[grow];
            if (wt != 0.0f) {
                float* op = out + (size_t)token * H_DIM + n0;
                #pragma unroll
                for (int ni = 0; ni < 4; ni++) {
                    int col = wn * 64 + ni * 16 + l15;
                    atomicAdd(op + col, wt * acc[mi][ni][r]);
                }
            }
        }
    }
}

extern "C" void kernel_launch(void* const* d_in, const int* in_sizes, int n_in,
                              void* d_out, int out_size, void* d_ws, size_t ws_size,
                              hipStream_t stream) {
    const float* x      = (const float*)d_in[0];
    const float* gate_w = (const float*)d_in[1];
    const float* w1     = (const float*)d_in[2];
    const float* w2     = (const float*)d_in[3];
    const float* ws1    = (const float*)d_in[4];
    const float* ws2    = (const float*)d_in[5];
    float* out = (float*)d_out;
    char* ws = (char*)d_ws;

    unsigned short* wt1  = (unsigned short*)(ws + OFF_WT1);
    unsigned short* wt2  = (unsigned short*)(ws + OFF_WT2);
    unsigned short* ws1t = (unsigned short*)(ws + OFF_WS1T);
    unsigned short* ws2t = (unsigned short*)(ws + OFF_WS2T);
    unsigned short* xb   = (unsigned short*)(ws + OFF_XB);
    unsigned short* hid  = (unsigned short*)(ws + OFF_HID);
    int*   rit  = (int*)(ws + OFF_RIT);
    float* riw  = (float*)(ws + OFF_RIW);
    int*   ctrl = (int*)(ws + OFF_CTRL);
    int*   tki  = (int*)(ws + OFF_TKI);
    float* tkw  = (float*)(ws + OFF_TKW);

    hipMemsetAsync(d_out, 0, (size_t)T_TOK * H_DIM * sizeof(float), stream);
    hipMemsetAsync(ws + OFF_RIT, 0, OFF_TKI - OFF_RIT, stream);

    transpose_cvt_kernel<<<dim3(N1 / 64, H_DIM / 64, E_NUM), 256, 0, stream>>>(w1, wt1, H_DIM, N1);
    transpose_cvt_kernel<<<dim3(H_DIM / 64, I_DIM / 64, E_NUM), 256, 0, stream>>>(w2, wt2, I_DIM, H_DIM);
    transpose_cvt_kernel<<<dim3(N1 / 64, H_DIM / 64, 1), 256, 0, stream>>>(ws1, ws1t, H_DIM, N1);
    transpose_cvt_kernel<<<dim3(H_DIM / 64, I_DIM / 64, 1), 256, 0, stream>>>(ws2, ws2t, I_DIM, H_DIM);
    cvt_x_kernel<<<(T_TOK * H_DIM / 8) / 256, 256, 0, stream>>>(x, xb);

    router_kernel<<<T_TOK, 64, 0, stream>>>(x, gate_w, tki, tkw, ctrl);
    prefix_kernel<<<1, 64, 0, stream>>>(ctrl);
    scatter_kernel<<<(3 * T_TOK + 255) / 256, 256, 0, stream>>>(tki, tkw, ctrl, rit, riw);

    gemm1_kernel<<<MAX_TILES * YB1, 256, 0, stream>>>(xb, wt1, ws1t, hid, rit, ctrl);
    gemm2_kernel<<<MAX_TILES * YB2, 256, 0, stream>>>(hid, wt2, ws2t, out, rit, riw, ctrl);
}